// Round 9
// baseline (1373.921 us; speedup 1.0000x reference)
//
#include <hip/hip_runtime.h>

typedef unsigned int  u32;
typedef unsigned short u16;

#define NND 100000
#define MPAD 100096
#define NE  3200000
#define F0  128
#define DIM 256
#define NC  16

// CSR bucketing
#define BSH   9
#define NBUCK 196
#define CAP   18432
#define EPB   8192

typedef __bf16 bf16x8 __attribute__((ext_vector_type(8)));
typedef float  f32x4  __attribute__((ext_vector_type(4)));

__device__ __forceinline__ float b2f(u16 h){ return __uint_as_float(((u32)h)<<16); }
__device__ __forceinline__ u16 f2b(float f){
    u32 u = __float_as_uint(f);
    return (u16)((u + 0x7fffu + ((u>>16)&1u)) >> 16);
}
__device__ __forceinline__ float lo16(u32 u){ return __uint_as_float(u<<16); }
__device__ __forceinline__ float hi16(u32 u){ return __uint_as_float(u & 0xffff0000u); }

// ---------------- probe + zero-init (gcur, statsA, statsB) ----------------
__global__ void probe_kernel(const u32* __restrict__ xw, const int* __restrict__ ei,
                             int* __restrict__ mode, int* __restrict__ gcur,
                             float* __restrict__ stats){
    int t = threadIdx.x;
    if(t < NBUCK) gcur[t] = 0;
    #pragma unroll
    for(int i=0;i<4;i++) stats[t + 256*i] = 0.f;
    if(t==0){
        int insane = 0;
        for(int i=0;i<64;i++){
            u32 w  = xw[i];
            u32 lo = w & 0xffffu;
            u32 e  = (lo >> 7) & 0xff;
            if(lo != 0 && (e < 48 || e > 208)) insane++;
        }
        mode[0] = (insane > 8) ? 1 : 0;
        int zeros = 0;
        for(int i=0;i<16;i++) if(ei[2*i+1]==0) zeros++;
        mode[1] = (zeros==16) ? 1 : 0;
    }
}

__device__ __forceinline__ int ld_src(const int* ei, int i64f, long e){
    return i64f ? ei[2*e] : ei[e];
}
__device__ __forceinline__ int ld_dst(const int* ei, int i64f, long e){
    return i64f ? ei[2*((long)NE + e)] : ei[(long)NE + e];
}

// ---------------- CSR build, Phase A ----------------
__global__ __launch_bounds__(256) void bucketA(const int* __restrict__ ei,
        const int* __restrict__ mode, u32* __restrict__ bucketArr,
        int* __restrict__ gcur){
    __shared__ u32 stag[EPB];
    __shared__ u16 sbuck[EPB];
    __shared__ int cnt[NBUCK];
    __shared__ int ofs[NBUCK];
    __shared__ int wofs[NBUCK];
    __shared__ int gbase[NBUCK];
    __shared__ int ps[256];
    int tid = threadIdx.x;
    int i64f = mode[1];
    long e0 = (long)blockIdx.x * EPB;
    int n = (int)min((long)EPB, (long)NE - e0);
    if(tid < NBUCK) cnt[tid] = 0;
    __syncthreads();
    for(int i=tid;i<n;i+=256){
        int d = ld_dst(ei, i64f, e0+i);
        atomicAdd(&cnt[d>>BSH], 1);
    }
    __syncthreads();
    ps[tid] = (tid < NBUCK) ? cnt[tid] : 0;
    __syncthreads();
    for(int o=1;o<256;o<<=1){
        int v = (tid>=o) ? ps[tid-o] : 0;
        __syncthreads();
        ps[tid] += v;
        __syncthreads();
    }
    if(tid < NBUCK){
        int ex = ps[tid] - cnt[tid];
        ofs[tid] = ex; wofs[tid] = ex;
        gbase[tid] = cnt[tid] ? atomicAdd(&gcur[tid], cnt[tid]) : 0;
    }
    __syncthreads();
    for(int i=tid;i<n;i+=256){
        int s = ld_src(ei, i64f, e0+i);
        int d = ld_dst(ei, i64f, e0+i);
        int b = d>>BSH;
        int r = atomicAdd(&wofs[b], 1);
        stag[r]  = ((u32)s<<BSH) | (u32)(d & ((1<<BSH)-1));
        sbuck[r] = (u16)b;
    }
    __syncthreads();
    for(int i=tid;i<n;i+=256){
        int b = sbuck[i];
        int pos = gbase[b] + (i - ofs[b]);
        if(pos < CAP) bucketArr[(size_t)b*CAP + pos] = stag[i];
    }
}

// ---------------- CSR build, Phase B ----------------
__global__ __launch_bounds__(256) void bucketB(const u32* __restrict__ bucketArr,
        const int* __restrict__ gcnt,
        int* __restrict__ rp, int* __restrict__ ssrc){
    __shared__ u32 stag[CAP];
    __shared__ int deg[512];
    __shared__ int lrp[512];
    __shared__ int cur[512];
    __shared__ int ps[256];
    int b = blockIdx.x, tid = threadIdx.x;
    ps[tid] = (tid < NBUCK) ? gcnt[tid] : 0;
    __syncthreads();
    for(int o=1;o<256;o<<=1){
        int v = (tid>=o) ? ps[tid-o] : 0;
        __syncthreads();
        ps[tid] += v;
        __syncthreads();
    }
    int base = (b>0) ? ps[b-1] : 0;
    int n = min(gcnt[b], CAP);
    const u32* ba = bucketArr + (size_t)b*CAP;
    deg[tid] = 0; deg[tid+256] = 0;
    __syncthreads();
    for(int i=tid;i<n;i+=256){
        atomicAdd(&deg[ba[i] & 511], 1);
    }
    __syncthreads();
    ps[tid] = deg[2*tid] + deg[2*tid+1];
    __syncthreads();
    for(int o=1;o<256;o<<=1){
        int v = (tid>=o) ? ps[tid-o] : 0;
        __syncthreads();
        ps[tid] += v;
        __syncthreads();
    }
    {
        int ep = (tid==0) ? 0 : ps[tid-1];
        lrp[2*tid]   = ep;
        lrp[2*tid+1] = ep + deg[2*tid];
        cur[2*tid]   = lrp[2*tid];
        cur[2*tid+1] = lrp[2*tid+1];
    }
    __syncthreads();
    for(int i=tid;i<512;i+=256){
        int node = (b<<BSH) + i;
        if(node <= NND) rp[node] = base + lrp[i];
    }
    for(int i=tid;i<n;i+=256){
        u32 v = ba[i];
        int r = atomicAdd(&cur[v & 511], 1);
        stag[r] = v >> BSH;
    }
    __syncthreads();
    for(int i=tid;i<n;i+=256){
        ssrc[base + i] = (int)stag[i];
    }
}

// ---------------- x canonicalization (f32 -> bf16) ----------------
__global__ void cvt_x(const float* __restrict__ xf, u16* __restrict__ Xc,
                      const int* __restrict__ mode){
    if(!mode[0]) return;
    size_t i = ((size_t)blockIdx.x*256 + threadIdx.x)*8;
    float4 a = *(const float4*)(xf+i);
    float4 b = *(const float4*)(xf+i+4);
    uint4 pk;
    pk.x = (u32)f2b(a.x) | ((u32)f2b(a.y)<<16);
    pk.y = (u32)f2b(a.z) | ((u32)f2b(a.w)<<16);
    pk.z = (u32)f2b(b.x) | ((u32)f2b(b.y)<<16);
    pk.w = (u32)f2b(b.z) | ((u32)f2b(b.w)<<16);
    *(uint4*)(Xc + i) = pk;
}

// ---------------- merged weight/bias canonicalization ----------------
__device__ __forceinline__ float ldf(const void* p, int i, int f32f){
    return f32f ? ((const float*)p)[i] : b2f(((const u16*)p)[i]);
}
__global__ void merged_cvt(
        const void* w1a, const void* w1b, const void* w2a, const void* w2b,
        const void* w3a, const void* w3b, const void* wfc,
        const void* b1a, const void* b1b, const void* g1, const void* be1,
        const void* b2a, const void* b2b, const void* g2, const void* be2,
        const void* b3a, const void* b3b, const void* bfcp,
        u16* __restrict__ Wt1a, u16* __restrict__ Wt1b, u16* __restrict__ Wt2a,
        u16* __restrict__ Wt2b, u16* __restrict__ Wt3a, u16* __restrict__ Wt3b,
        u16* __restrict__ Wfc, u16* __restrict__ Vc, const int* __restrict__ mode){
    int b = blockIdx.x, t = threadIdx.x;
    int f32f = mode[0];
    if(b < 128){
        int id = b*256 + t;
        int k = id / DIM, n = id % DIM;
        Wt1a[n*F0 + k] = f2b(ldf(w1a, id, f32f));
        return;
    }
    b -= 128;
    if(b < 5*256){
        int wi = b >> 8;
        const void* W = (wi==0)?w1b:(wi==1)?w2a:(wi==2)?w2b:(wi==3)?w3a:w3b;
        u16* Wt = (wi==0)?Wt1b:(wi==1)?Wt2a:(wi==2)?Wt2b:(wi==3)?Wt3a:Wt3b;
        int id = (b & 255)*256 + t;
        int k = id / DIM, n = id % DIM;
        Wt[n*DIM + k] = f2b(ldf(W, id, f32f));
        return;
    }
    b -= 5*256;
    if(b < 16){
        int id = b*256 + t;
        int k = id / NC, c = id % NC;
        Wfc[c*DIM + k] = f2b(ldf(wfc, id, f32f));
        return;
    }
    b -= 16;
    {
        const void* ps[11] = {b1a,b1b,g1,be1,b2a,b2b,g2,be2,b3a,b3b,bfcp};
        int lens[11] = {DIM,DIM,DIM,DIM,DIM,DIM,DIM,DIM,DIM,DIM,NC};
        if(t < lens[b]) Vc[b*256 + t] = f2b(ldf(ps[b], t, f32f));
    }
}

// ---------------- fully fused layer: agg(+BN affine) -> MLP -> [stats | FC+lsm] ----
// Block = 64 nodes. Agg results land in LDS (never global); z also LDS.
#define FBM 64
#define ZP  264          // z / aggout(K=256) stride: 2-way LDS conflicts only (free)
template<int KA>
__global__ __launch_bounds__(256) void layer_fused(
        const u16* __restrict__ hA, const u16* __restrict__ hB,
        const int* __restrict__ mode,
        const int* __restrict__ rp, const int* __restrict__ ssrc,
        const float* __restrict__ statsIn, const u16* __restrict__ g,
        const u16* __restrict__ be, int use_bn,
        const u16* __restrict__ WaT, const u16* __restrict__ ba,
        const u16* __restrict__ WbT, const u16* __restrict__ bb,
        u16* __restrict__ C, float* __restrict__ statsOut, int do_stats,
        int do_fc, const u16* __restrict__ WfcT, const u16* __restrict__ bfc,
        void* __restrict__ out){
    const int AP = KA + 8;                        // aggout stride
    __shared__ __align__(16) u16 zt[FBM*ZP];      // aggout then z (34 KB)
    __shared__ float colS[DIM], colS2[DIM];
    int tid = threadIdx.x;
    int w = tid>>6, lane = tid&63;
    int q = lane>>4, mr = lane&15;
    int m0 = blockIdx.x*FBM;

    if(do_stats){ colS[tid]=0.f; colS2[tid]=0.f; }

    // ---- agg phase: each wave aggregates 16 nodes into zt (stride AP) ----
    {
        const int LPI = KA/8;        // lanes per item
        const int IPW = 64/LPI;      // items per wave
        int li   = lane & (LPI-1);
        int slot = lane / LPI;
        int boff = li*8;
        const u16* h = mode[0] ? hB : hA;

        float aff_a[8], aff_b[8];
        if(use_bn){
            float inv_m = 1.0f / (float)NND;
            #pragma unroll
            for(int j=0;j<8;j++){
                int f = boff + j;
                float mean = statsIn[f]*inv_m;
                float var  = fmaxf(statsIn[KA+f]*inv_m - mean*mean, 0.f);
                float rstd = rsqrtf(var + 1e-5f);
                float gg = b2f(g[f]);
                aff_a[j] = gg*rstd;
                aff_b[j] = b2f(be[f]) - aff_a[j]*mean;
            }
        } else {
            #pragma unroll
            for(int j=0;j<8;j++){ aff_a[j]=1.f; aff_b[j]=0.f; }
        }

        for(int nl = w; nl < FBM; nl += 4){
            int node = m0 + nl;
            float acc[8] = {0.f,0.f,0.f,0.f,0.f,0.f,0.f,0.f};
            float cnt = 0.f;
            if(node < NND){
                int e0 = rp[node], e1 = rp[node+1];
                int n_items = e1 - e0 + 1;
                cnt = (float)n_items;
                auto item = [&](int idx)->int { return (idx==0) ? node : ssrc[e0 + idx - 1]; };
                auto addu = [&](uint4 u){
                    acc[0]+=lo16(u.x); acc[1]+=hi16(u.x);
                    acc[2]+=lo16(u.y); acc[3]+=hi16(u.y);
                    acc[4]+=lo16(u.z); acc[5]+=hi16(u.z);
                    acc[6]+=lo16(u.w); acc[7]+=hi16(u.w);
                };
                int i = 0;
                for(; i + 4*IPW <= n_items; i += 4*IPW){
                    int s0 = item(i + slot);
                    int s1 = item(i + IPW + slot);
                    int s2 = item(i + 2*IPW + slot);
                    int s3 = item(i + 3*IPW + slot);
                    uint4 u0 = *(const uint4*)(h + (size_t)s0*KA + boff);
                    uint4 u1 = *(const uint4*)(h + (size_t)s1*KA + boff);
                    uint4 u2 = *(const uint4*)(h + (size_t)s2*KA + boff);
                    uint4 u3 = *(const uint4*)(h + (size_t)s3*KA + boff);
                    addu(u0); addu(u1); addu(u2); addu(u3);
                }
                for(; i + IPW <= n_items; i += IPW){
                    int s = item(i + slot);
                    addu(*(const uint4*)(h + (size_t)s*KA + boff));
                }
                if(i < n_items && slot < n_items - i){
                    int s = item(i + slot);
                    addu(*(const uint4*)(h + (size_t)s*KA + boff));
                }
            }
            #pragma unroll
            for(int j=0;j<8;j++){
                if(LPI==16) acc[j] += __shfl_xor(acc[j], 16);
                acc[j] += __shfl_xor(acc[j], 32);
            }
            if(slot == 0){
                uint4 o;
                float r0 = aff_a[0]*acc[0] + cnt*aff_b[0];
                float r1 = aff_a[1]*acc[1] + cnt*aff_b[1];
                float r2 = aff_a[2]*acc[2] + cnt*aff_b[2];
                float r3 = aff_a[3]*acc[3] + cnt*aff_b[3];
                float r4 = aff_a[4]*acc[4] + cnt*aff_b[4];
                float r5 = aff_a[5]*acc[5] + cnt*aff_b[5];
                float r6 = aff_a[6]*acc[6] + cnt*aff_b[6];
                float r7 = aff_a[7]*acc[7] + cnt*aff_b[7];
                o.x = (u32)f2b(r0) | ((u32)f2b(r1)<<16);
                o.y = (u32)f2b(r2) | ((u32)f2b(r3)<<16);
                o.z = (u32)f2b(r4) | ((u32)f2b(r5)<<16);
                o.w = (u32)f2b(r6) | ((u32)f2b(r7)<<16);
                *(uint4*)(&zt[nl*AP + boff]) = o;
            }
        }
    }
    __syncthreads();

    f32x4 acc[4][4];
    #pragma unroll
    for(int i=0;i<4;i++)
        #pragma unroll
        for(int c=0;c<4;c++) acc[i][c] = (f32x4){0.f,0.f,0.f,0.f};

    // ---- phase 1: acc = aggout @ Wa  (A from LDS, Wa prefetched from global) ----
    {
        const int NK = KA/32;
        bf16x8 b0[4];
        #pragma unroll
        for(int c=0;c<4;c++)
            b0[c] = *reinterpret_cast<const bf16x8*>(WaT + (size_t)(w*64 + c*16 + mr)*KA + q*8);
        #pragma unroll
        for(int k=0;k<NK;k++){
            bf16x8 b1[4];
            if(k+1<NK){
                #pragma unroll
                for(int c=0;c<4;c++)
                    b1[c] = *reinterpret_cast<const bf16x8*>(WaT + (size_t)(w*64 + c*16 + mr)*KA + (k+1)*32 + q*8);
            }
            bf16x8 af[4];
            #pragma unroll
            for(int i=0;i<4;i++)
                af[i] = *reinterpret_cast<const bf16x8*>(&zt[(i*16+mr)*AP + k*32 + q*8]);
            #pragma unroll
            for(int i=0;i<4;i++)
                #pragma unroll
                for(int c=0;c<4;c++)
                    acc[i][c] = __builtin_amdgcn_mfma_f32_16x16x32_bf16(af[i], b0[c], acc[i][c], 0, 0, 0);
            if(k+1<NK){
                #pragma unroll
                for(int c=0;c<4;c++) b0[c]=b1[c];
            }
        }
    }
    __syncthreads();   // aggout fully consumed; zt can be overwritten with z

    // z = relu(acc + ba) -> LDS (stride ZP), reset acc
    #pragma unroll
    for(int c=0;c<4;c++){
        int col = w*64 + c*16 + mr;
        float bav = b2f(ba[col]);
        #pragma unroll
        for(int i=0;i<4;i++){
            #pragma unroll
            for(int r=0;r<4;r++){
                int row = i*16 + q*4 + r;
                zt[row*ZP + col] = f2b(fmaxf(acc[i][c][r] + bav, 0.f));
            }
            acc[i][c] = (f32x4){0.f,0.f,0.f,0.f};
        }
    }
    __syncthreads();

    // ---- phase 2: acc = z @ Wb  (z from LDS, Wb prefetched) ----
    {
        const int NK = DIM/32;
        bf16x8 b0[4];
        #pragma unroll
        for(int c=0;c<4;c++)
            b0[c] = *reinterpret_cast<const bf16x8*>(WbT + (size_t)(w*64 + c*16 + mr)*DIM + q*8);
        #pragma unroll
        for(int k=0;k<NK;k++){
            bf16x8 b1[4];
            if(k+1<NK){
                #pragma unroll
                for(int c=0;c<4;c++)
                    b1[c] = *reinterpret_cast<const bf16x8*>(WbT + (size_t)(w*64 + c*16 + mr)*DIM + (k+1)*32 + q*8);
            }
            bf16x8 af[4];
            #pragma unroll
            for(int i=0;i<4;i++)
                af[i] = *reinterpret_cast<const bf16x8*>(&zt[(i*16+mr)*ZP + k*32 + q*8]);
            #pragma unroll
            for(int i=0;i<4;i++)
                #pragma unroll
                for(int c=0;c<4;c++)
                    acc[i][c] = __builtin_amdgcn_mfma_f32_16x16x32_bf16(af[i], b0[c], acc[i][c], 0, 0, 0);
            if(k+1<NK){
                #pragma unroll
                for(int c=0;c<4;c++) b0[c]=b1[c];
            }
        }
    }

    if(!do_fc){
        // ---- epilogue: bias + relu + store C + fused BN stats ----
        #pragma unroll
        for(int c=0;c<4;c++){
            int col = w*64 + c*16 + mr;
            float bv = b2f(bb[col]);
            float s = 0.f, s2 = 0.f;
            #pragma unroll
            for(int i=0;i<4;i++){
                int row = m0 + i*16 + q*4;
                #pragma unroll
                for(int r=0;r<4;r++){
                    float v = fmaxf(acc[i][c][r] + bv, 0.f);
                    u16 o = f2b(v);
                    C[(size_t)(row + r)*DIM + col] = o;
                    if(do_stats && (row + r) < NND){
                        float vr = b2f(o);
                        s += vr; s2 += vr*vr;
                    }
                }
            }
            if(do_stats){
                atomicAdd(&colS[col], s);
                atomicAdd(&colS2[col], s2);
            }
        }
        if(do_stats){
            __syncthreads();
            atomicAdd(&statsOut[tid], colS[tid]);
            atomicAdd(&statsOut[DIM+tid], colS2[tid]);
        }
    } else {
        // ---- layer-3 epilogue: h3 -> LDS, FC via MFMA, log-softmax, store out ----
        __syncthreads();
        #pragma unroll
        for(int c=0;c<4;c++){
            int col = w*64 + c*16 + mr;
            float bv = b2f(bb[col]);
            #pragma unroll
            for(int i=0;i<4;i++)
                #pragma unroll
                for(int r=0;r<4;r++)
                    zt[(i*16 + q*4 + r)*ZP + col] = f2b(fmaxf(acc[i][c][r] + bv, 0.f));
        }
        __syncthreads();
        f32x4 fa = (f32x4){0.f,0.f,0.f,0.f};
        #pragma unroll
        for(int k0=0; k0<DIM; k0+=32){
            bf16x8 za = *reinterpret_cast<const bf16x8*>(&zt[(w*16+mr)*ZP + k0 + q*8]);
            bf16x8 wb = *reinterpret_cast<const bf16x8*>(WfcT + (size_t)mr*DIM + k0 + q*8);
            fa = __builtin_amdgcn_mfma_f32_16x16x32_bf16(za, wb, fa, 0, 0, 0);
        }
        float bv = b2f(bfc[mr]);
        int f32o = mode[0];
        #pragma unroll
        for(int r=0;r<4;r++){
            float val = fa[r] + bv;
            float m = val;
            #pragma unroll
            for(int o=1;o<16;o<<=1) m = fmaxf(m, __shfl_xor(m, o));
            float ex = expf(val - m);
            float s = ex;
            #pragma unroll
            for(int o=1;o<16;o<<=1) s += __shfl_xor(s, o);
            float res = val - m - logf(s);
            int row = m0 + w*16 + q*4 + r;
            if(row < NND){
                if(f32o) ((float*)out)[(size_t)row*NC + mr] = res;
                else     ((u16*)out)[(size_t)row*NC + mr] = f2b(res);
            }
        }
    }
}

extern "C" void kernel_launch(void* const* d_in, const int* in_sizes, int n_in,
                              void* d_out, int out_size, void* d_ws, size_t ws_size,
                              hipStream_t stream){
    const void* x   = d_in[0];
    const int*  ei  = (const int*)d_in[1];
    const void* w1a = d_in[2];  const void* b1a = d_in[3];
    const void* w1b = d_in[4];  const void* b1b = d_in[5];
    const void* g1  = d_in[6];  const void* be1 = d_in[7];
    const void* w2a = d_in[8];  const void* b2a = d_in[9];
    const void* w2b = d_in[10]; const void* b2b = d_in[11];
    const void* g2  = d_in[12]; const void* be2 = d_in[13];
    const void* w3a = d_in[14]; const void* b3a = d_in[15];
    const void* w3b = d_in[16]; const void* b3b = d_in[17];
    const void* wfc = d_in[18]; const void* bfc = d_in[19];

    char* base = (char*)d_ws;
    size_t off = 0;
    auto alloc = [&](size_t bytes)->void*{
        void* p = base + off;
        off = (off + bytes + 255) & ~(size_t)255;
        return p;
    };
    u16*  P     = (u16*)alloc((size_t)MPAD*DIM*2);   // layer-1 output
    u16*  Q     = (u16*)alloc((size_t)MPAD*DIM*2);   // Xc alias, then layer-2 output
    int*  ssrc  = (int*)alloc((size_t)NE*4);
    u32*  bArr  = (u32*)alloc((size_t)NBUCK*CAP*4);
    int*  gcur  = (int*)alloc((size_t)NBUCK*4);
    int*  rp    = (int*)alloc((size_t)(NND+1)*4);
    float* stats= (float*)alloc(4*DIM*4);            // statsA | statsB
    int*  mode  = (int*)alloc(16);
    u16* Wt1a = (u16*)alloc((size_t)F0*DIM*2);
    u16* Wt1b = (u16*)alloc((size_t)DIM*DIM*2);
    u16* Wt2a = (u16*)alloc((size_t)DIM*DIM*2);
    u16* Wt2b = (u16*)alloc((size_t)DIM*DIM*2);
    u16* Wt3a = (u16*)alloc((size_t)DIM*DIM*2);
    u16* Wt3b = (u16*)alloc((size_t)DIM*DIM*2);
    u16* Vc   = (u16*)alloc(11*256*2);
    u16* Wfc  = (u16*)alloc((size_t)DIM*NC*2);
    u16* Xc   = Q;   // alias: dead after layer 1; layer 2 then overwrites Q as output
    float* statsA = stats;
    float* statsB = stats + 2*DIM;

    probe_kernel<<<1, 256, 0, stream>>>((const u32*)x, ei, mode, gcur, stats);

    bucketA<<<(NE + EPB - 1)/EPB, 256, 0, stream>>>(ei, mode, bArr, gcur);
    bucketB<<<NBUCK, 256, 0, stream>>>(bArr, gcur, rp, ssrc);

    cvt_x<<<(NND*F0)/(256*8), 256, 0, stream>>>((const float*)x, Xc, mode);
    merged_cvt<<<128 + 5*256 + 16 + 11, 256, 0, stream>>>(
        w1a,w1b,w2a,w2b,w3a,w3b,wfc, b1a,b1b,g1,be1,b2a,b2b,g2,be2,b3a,b3b,bfc,
        Wt1a,Wt1b,Wt2a,Wt2b,Wt3a,Wt3b,Wfc,Vc, mode);

    int mgrid = MPAD/FBM;   // 1564

    // ---- layer 1: gather x/Xc -> MLP1 -> P (+BN1 stats) ----
    layer_fused<F0><<<mgrid, 256, 0, stream>>>(
        (const u16*)x, Xc, mode, rp, ssrc,
        statsA, Vc, Vc, 0,
        Wt1a, Vc+0*256, Wt1b, Vc+1*256,
        P, statsA, 1, 0, Wfc, Vc+10*256, d_out);

    // ---- layer 2: gather P (BN1 affine) -> MLP2 -> Q (+BN2 stats) ----
    layer_fused<DIM><<<mgrid, 256, 0, stream>>>(
        P, P, mode, rp, ssrc,
        statsA, Vc+2*256, Vc+3*256, 1,
        Wt2a, Vc+4*256, Wt2b, Vc+5*256,
        Q, statsB, 1, 0, Wfc, Vc+10*256, d_out);

    // ---- layer 3: gather Q (BN2 affine) -> MLP3 -> FC + log_softmax -> out ----
    layer_fused<DIM><<<mgrid, 256, 0, stream>>>(
        Q, Q, mode, rp, ssrc,
        statsB, Vc+6*256, Vc+7*256, 1,
        Wt3a, Vc+8*256, Wt3b, Vc+9*256,
        P, statsA, 0, 1, Wfc, Vc+10*256, d_out);
}

// Round 10
// 1044.896 us; speedup vs baseline: 1.3149x; 1.3149x over previous
//
#include <hip/hip_runtime.h>

typedef unsigned int  u32;
typedef unsigned short u16;

#define NND 100000
#define MPAD 100096
#define NE  3200000
#define F0  128
#define DIM 256
#define NC  16

// CSR bucketing
#define BSH   9
#define NBUCK 196
#define CAP   18432
#define EPB   8192

typedef __bf16 bf16x8 __attribute__((ext_vector_type(8)));
typedef float  f32x4  __attribute__((ext_vector_type(4)));

__device__ __forceinline__ float b2f(u16 h){ return __uint_as_float(((u32)h)<<16); }
__device__ __forceinline__ u16 f2b(float f){
    u32 u = __float_as_uint(f);
    return (u16)((u + 0x7fffu + ((u>>16)&1u)) >> 16);
}
__device__ __forceinline__ float lo16(u32 u){ return __uint_as_float(u<<16); }
__device__ __forceinline__ float hi16(u32 u){ return __uint_as_float(u & 0xffff0000u); }

// ---------------- probe + zero-init (gcur, statsA, statsB) ----------------
__global__ void probe_kernel(const u32* __restrict__ xw, const int* __restrict__ ei,
                             int* __restrict__ mode, int* __restrict__ gcur,
                             float* __restrict__ stats){
    int t = threadIdx.x;
    if(t < NBUCK) gcur[t] = 0;
    #pragma unroll
    for(int i=0;i<4;i++) stats[t + 256*i] = 0.f;
    if(t==0){
        int insane = 0;
        for(int i=0;i<64;i++){
            u32 w  = xw[i];
            u32 lo = w & 0xffffu;
            u32 e  = (lo >> 7) & 0xff;
            if(lo != 0 && (e < 48 || e > 208)) insane++;
        }
        mode[0] = (insane > 8) ? 1 : 0;
        int zeros = 0;
        for(int i=0;i<16;i++) if(ei[2*i+1]==0) zeros++;
        mode[1] = (zeros==16) ? 1 : 0;
    }
}

__device__ __forceinline__ int ld_src(const int* ei, int i64f, long e){
    return i64f ? ei[2*e] : ei[e];
}
__device__ __forceinline__ int ld_dst(const int* ei, int i64f, long e){
    return i64f ? ei[2*((long)NE + e)] : ei[(long)NE + e];
}

// ---------------- CSR build, Phase A ----------------
__global__ __launch_bounds__(256) void bucketA(const int* __restrict__ ei,
        const int* __restrict__ mode, u32* __restrict__ bucketArr,
        int* __restrict__ gcur){
    __shared__ u32 stag[EPB];
    __shared__ u16 sbuck[EPB];
    __shared__ int cnt[NBUCK];
    __shared__ int ofs[NBUCK];
    __shared__ int wofs[NBUCK];
    __shared__ int gbase[NBUCK];
    __shared__ int ps[256];
    int tid = threadIdx.x;
    int i64f = mode[1];
    long e0 = (long)blockIdx.x * EPB;
    int n = (int)min((long)EPB, (long)NE - e0);
    if(tid < NBUCK) cnt[tid] = 0;
    __syncthreads();
    for(int i=tid;i<n;i+=256){
        int d = ld_dst(ei, i64f, e0+i);
        atomicAdd(&cnt[d>>BSH], 1);
    }
    __syncthreads();
    ps[tid] = (tid < NBUCK) ? cnt[tid] : 0;
    __syncthreads();
    for(int o=1;o<256;o<<=1){
        int v = (tid>=o) ? ps[tid-o] : 0;
        __syncthreads();
        ps[tid] += v;
        __syncthreads();
    }
    if(tid < NBUCK){
        int ex = ps[tid] - cnt[tid];
        ofs[tid] = ex; wofs[tid] = ex;
        gbase[tid] = cnt[tid] ? atomicAdd(&gcur[tid], cnt[tid]) : 0;
    }
    __syncthreads();
    for(int i=tid;i<n;i+=256){
        int s = ld_src(ei, i64f, e0+i);
        int d = ld_dst(ei, i64f, e0+i);
        int b = d>>BSH;
        int r = atomicAdd(&wofs[b], 1);
        stag[r]  = ((u32)s<<BSH) | (u32)(d & ((1<<BSH)-1));
        sbuck[r] = (u16)b;
    }
    __syncthreads();
    for(int i=tid;i<n;i+=256){
        int b = sbuck[i];
        int pos = gbase[b] + (i - ofs[b]);
        if(pos < CAP) bucketArr[(size_t)b*CAP + pos] = stag[i];
    }
}

// ---------------- CSR build, Phase B ----------------
__global__ __launch_bounds__(256) void bucketB(const u32* __restrict__ bucketArr,
        const int* __restrict__ gcnt,
        int* __restrict__ rp, int* __restrict__ ssrc){
    __shared__ u32 stag[CAP];
    __shared__ int deg[512];
    __shared__ int lrp[512];
    __shared__ int cur[512];
    __shared__ int ps[256];
    int b = blockIdx.x, tid = threadIdx.x;
    ps[tid] = (tid < NBUCK) ? gcnt[tid] : 0;
    __syncthreads();
    for(int o=1;o<256;o<<=1){
        int v = (tid>=o) ? ps[tid-o] : 0;
        __syncthreads();
        ps[tid] += v;
        __syncthreads();
    }
    int base = (b>0) ? ps[b-1] : 0;
    int n = min(gcnt[b], CAP);
    const u32* ba = bucketArr + (size_t)b*CAP;
    deg[tid] = 0; deg[tid+256] = 0;
    __syncthreads();
    for(int i=tid;i<n;i+=256){
        atomicAdd(&deg[ba[i] & 511], 1);
    }
    __syncthreads();
    ps[tid] = deg[2*tid] + deg[2*tid+1];
    __syncthreads();
    for(int o=1;o<256;o<<=1){
        int v = (tid>=o) ? ps[tid-o] : 0;
        __syncthreads();
        ps[tid] += v;
        __syncthreads();
    }
    {
        int ep = (tid==0) ? 0 : ps[tid-1];
        lrp[2*tid]   = ep;
        lrp[2*tid+1] = ep + deg[2*tid];
        cur[2*tid]   = lrp[2*tid];
        cur[2*tid+1] = lrp[2*tid+1];
    }
    __syncthreads();
    for(int i=tid;i<512;i+=256){
        int node = (b<<BSH) + i;
        if(node <= NND) rp[node] = base + lrp[i];
    }
    for(int i=tid;i<n;i+=256){
        u32 v = ba[i];
        int r = atomicAdd(&cur[v & 511], 1);
        stag[r] = v >> BSH;
    }
    __syncthreads();
    for(int i=tid;i<n;i+=256){
        ssrc[base + i] = (int)stag[i];
    }
}

// ---------------- x canonicalization (f32 -> bf16) ----------------
__global__ void cvt_x(const float* __restrict__ xf, u16* __restrict__ Xc,
                      const int* __restrict__ mode){
    if(!mode[0]) return;
    size_t i = ((size_t)blockIdx.x*256 + threadIdx.x)*8;
    float4 a = *(const float4*)(xf+i);
    float4 b = *(const float4*)(xf+i+4);
    uint4 pk;
    pk.x = (u32)f2b(a.x) | ((u32)f2b(a.y)<<16);
    pk.y = (u32)f2b(a.z) | ((u32)f2b(a.w)<<16);
    pk.z = (u32)f2b(b.x) | ((u32)f2b(b.y)<<16);
    pk.w = (u32)f2b(b.z) | ((u32)f2b(b.w)<<16);
    *(uint4*)(Xc + i) = pk;
}

// ---------------- merged weight/bias canonicalization ----------------
__device__ __forceinline__ float ldf(const void* p, int i, int f32f){
    return f32f ? ((const float*)p)[i] : b2f(((const u16*)p)[i]);
}
__global__ void merged_cvt(
        const void* w1a, const void* w1b, const void* w2a, const void* w2b,
        const void* w3a, const void* w3b, const void* wfc,
        const void* b1a, const void* b1b, const void* g1, const void* be1,
        const void* b2a, const void* b2b, const void* g2, const void* be2,
        const void* b3a, const void* b3b, const void* bfcp,
        u16* __restrict__ Wt1a, u16* __restrict__ Wt1b, u16* __restrict__ Wt2a,
        u16* __restrict__ Wt2b, u16* __restrict__ Wt3a, u16* __restrict__ Wt3b,
        u16* __restrict__ Wfc, u16* __restrict__ Vc, const int* __restrict__ mode){
    int b = blockIdx.x, t = threadIdx.x;
    int f32f = mode[0];
    if(b < 128){
        int id = b*256 + t;
        int k = id / DIM, n = id % DIM;
        Wt1a[n*F0 + k] = f2b(ldf(w1a, id, f32f));
        return;
    }
    b -= 128;
    if(b < 5*256){
        int wi = b >> 8;
        const void* W = (wi==0)?w1b:(wi==1)?w2a:(wi==2)?w2b:(wi==3)?w3a:w3b;
        u16* Wt = (wi==0)?Wt1b:(wi==1)?Wt2a:(wi==2)?Wt2b:(wi==3)?Wt3a:Wt3b;
        int id = (b & 255)*256 + t;
        int k = id / DIM, n = id % DIM;
        Wt[n*DIM + k] = f2b(ldf(W, id, f32f));
        return;
    }
    b -= 5*256;
    if(b < 16){
        int id = b*256 + t;
        int k = id / NC, c = id % NC;
        Wfc[c*DIM + k] = f2b(ldf(wfc, id, f32f));
        return;
    }
    b -= 16;
    {
        const void* ps[11] = {b1a,b1b,g1,be1,b2a,b2b,g2,be2,b3a,b3b,bfcp};
        int lens[11] = {DIM,DIM,DIM,DIM,DIM,DIM,DIM,DIM,DIM,DIM,NC};
        if(t < lens[b]) Vc[b*256 + t] = f2b(ldf(ps[b], t, f32f));
    }
}

// ---------------- aggregation: 16B lanes, unroll-8 (round-8 proven version) --------
template<int LPI>
__global__ __launch_bounds__(256) void agg2(const u16* __restrict__ hA,
        const u16* __restrict__ hB, const int* __restrict__ mode,
        const int* __restrict__ rp, const int* __restrict__ ssrc,
        u16* __restrict__ out,
        const float* __restrict__ stats, const u16* __restrict__ g,
        const u16* __restrict__ be, int use_bn, int M){
    const int F = LPI*8;
    const int IPW = 64/LPI;
    int node = blockIdx.x*4 + (threadIdx.x>>6);
    if(node >= M) return;
    int lane = threadIdx.x & 63;
    int li   = lane & (LPI-1);
    int slot = lane / LPI;
    const u16* h = (LPI==16 && mode[0]) ? hB : hA;
    const int boff = li*8;

    int e0 = rp[node], e1 = rp[node+1];
    int n_items = e1 - e0 + 1;
    float acc[8] = {0.f,0.f,0.f,0.f,0.f,0.f,0.f,0.f};

    auto item = [&](int i)->int { return (i==0) ? node : ssrc[e0 + i - 1]; };
    auto addu = [&](uint4 u){
        acc[0]+=lo16(u.x); acc[1]+=hi16(u.x);
        acc[2]+=lo16(u.y); acc[3]+=hi16(u.y);
        acc[4]+=lo16(u.z); acc[5]+=hi16(u.z);
        acc[6]+=lo16(u.w); acc[7]+=hi16(u.w);
    };

    int i = 0;
    for(; i + 8*IPW <= n_items; i += 8*IPW){
        int s[8];
        #pragma unroll
        for(int j=0;j<8;j++) s[j] = item(i + j*IPW + slot);
        uint4 u[8];
        #pragma unroll
        for(int j=0;j<8;j++) u[j] = *(const uint4*)(h + (size_t)s[j]*F + boff);
        #pragma unroll
        for(int j=0;j<8;j++) addu(u[j]);
    }
    for(; i + IPW <= n_items; i += IPW){
        int s = item(i + slot);
        addu(*(const uint4*)(h + (size_t)s*F + boff));
    }
    if(i < n_items){
        int r = n_items - i;
        if(slot < r){
            int s = item(i + slot);
            addu(*(const uint4*)(h + (size_t)s*F + boff));
        }
    }

    #pragma unroll
    for(int j=0;j<8;j++){
        if(LPI==16) acc[j] += __shfl_xor(acc[j], 16);
        acc[j] += __shfl_xor(acc[j], 32);
    }

    if(slot == 0){
        float res[8];
        if(use_bn){
            float inv_m = 1.0f / (float)M;
            float cnt = (float)n_items;
            #pragma unroll
            for(int j=0;j<8;j++){
                int f = boff + j;
                float mean = stats[f]*inv_m;
                float var  = fmaxf(stats[F+f]*inv_m - mean*mean, 0.f);
                float rstd = rsqrtf(var + 1e-5f);
                float gg = b2f(g[f]);
                float a = gg*rstd;
                float bb = b2f(be[f]) - a*mean;
                res[j] = a*acc[j] + cnt*bb;
            }
        } else {
            #pragma unroll
            for(int j=0;j<8;j++) res[j] = acc[j];
        }
        uint4 o;
        o.x = (u32)f2b(res[0]) | ((u32)f2b(res[1])<<16);
        o.y = (u32)f2b(res[2]) | ((u32)f2b(res[3])<<16);
        o.z = (u32)f2b(res[4]) | ((u32)f2b(res[5])<<16);
        o.w = (u32)f2b(res[6]) | ((u32)f2b(res[7])<<16);
        *(uint4*)(out + (size_t)node*F + boff) = o;
    }
}

// ---------------- fused per-layer MLP: A staged once in LDS, B reg-prefetched ------
// C = relu(relu(A@Wa+ba)@Wb+bb). A-tile and z share one LDS buffer (A dead first).
#define FBM 64
#define ZP  264          // z stride; A stride = KA+8: both give free 2-way conflicts
template<int KA>
__global__ __launch_bounds__(256) void mlp_fused(
        const u16* __restrict__ A, const u16* __restrict__ WaT,
        const u16* __restrict__ ba, const u16* __restrict__ WbT,
        const u16* __restrict__ bb, u16* __restrict__ C,
        float* __restrict__ stats, int do_stats,
        int do_fc, const u16* __restrict__ WfcT, const u16* __restrict__ bfc,
        void* __restrict__ out, const int* __restrict__ mode){
    const int APAD = KA + 8;
    __shared__ __align__(16) u16 zt[FBM*ZP];      // 33 KB, holds A-tile then z
    __shared__ float colS[DIM], colS2[DIM];
    int tid = threadIdx.x;
    int w = tid>>6, lane = tid&63;
    int q = lane>>4, mr = lane&15;
    int m0 = blockIdx.x*FBM;

    if(do_stats){ colS[tid]=0.f; colS2[tid]=0.f; }

    // ---- stage A-tile (64 x KA) into LDS once, padded stride APAD ----
    {
        const int CH = KA/8;              // 16B chunks per row
        #pragma unroll
        for(int j=0;j<64*8/256*(KA/64);j++){   // (64*CH)/256 iterations
            int idx = j*256 + tid;
            int r = idx / CH, c = idx - r*CH;
            uint4 v = *(const uint4*)(A + (size_t)(m0 + r)*KA + c*8);
            *(uint4*)(&zt[r*APAD + c*8]) = v;
        }
    }
    __syncthreads();

    f32x4 acc[4][4];
    #pragma unroll
    for(int i=0;i<4;i++)
        #pragma unroll
        for(int c=0;c<4;c++) acc[i][c] = (f32x4){0.f,0.f,0.f,0.f};

    // ---- phase 1: acc = A @ Wa  (A from LDS, Wa reg-prefetched from L2) ----
    {
        const int NK = KA/32;
        bf16x8 b0[4];
        #pragma unroll
        for(int c=0;c<4;c++)
            b0[c] = *reinterpret_cast<const bf16x8*>(WaT + (size_t)(w*64 + c*16 + mr)*KA + q*8);
        #pragma unroll
        for(int k=0;k<NK;k++){
            bf16x8 b1[4];
            if(k+1<NK){
                #pragma unroll
                for(int c=0;c<4;c++)
                    b1[c] = *reinterpret_cast<const bf16x8*>(WaT + (size_t)(w*64 + c*16 + mr)*KA + (k+1)*32 + q*8);
            }
            bf16x8 af[4];
            #pragma unroll
            for(int i=0;i<4;i++)
                af[i] = *reinterpret_cast<const bf16x8*>(&zt[(i*16+mr)*APAD + k*32 + q*8]);
            #pragma unroll
            for(int i=0;i<4;i++)
                #pragma unroll
                for(int c=0;c<4;c++)
                    acc[i][c] = __builtin_amdgcn_mfma_f32_16x16x32_bf16(af[i], b0[c], acc[i][c], 0, 0, 0);
            if(k+1<NK){
                #pragma unroll
                for(int c=0;c<4;c++) b0[c]=b1[c];
            }
        }
    }
    __syncthreads();   // A-tile fully consumed; buffer becomes z

    // z = relu(acc + ba) -> LDS (stride ZP), reset acc
    #pragma unroll
    for(int c=0;c<4;c++){
        int col = w*64 + c*16 + mr;
        float bav = b2f(ba[col]);
        #pragma unroll
        for(int i=0;i<4;i++){
            #pragma unroll
            for(int r=0;r<4;r++){
                int row = i*16 + q*4 + r;
                zt[row*ZP + col] = f2b(fmaxf(acc[i][c][r] + bav, 0.f));
            }
            acc[i][c] = (f32x4){0.f,0.f,0.f,0.f};
        }
    }
    __syncthreads();

    // ---- phase 2: acc = z @ Wb  (z from LDS, Wb reg-prefetched) ----
    {
        const int NK = DIM/32;
        bf16x8 b0[4];
        #pragma unroll
        for(int c=0;c<4;c++)
            b0[c] = *reinterpret_cast<const bf16x8*>(WbT + (size_t)(w*64 + c*16 + mr)*DIM + q*8);
        #pragma unroll
        for(int k=0;k<NK;k++){
            bf16x8 b1[4];
            if(k+1<NK){
                #pragma unroll
                for(int c=0;c<4;c++)
                    b1[c] = *reinterpret_cast<const bf16x8*>(WbT + (size_t)(w*64 + c*16 + mr)*DIM + (k+1)*32 + q*8);
            }
            bf16x8 af[4];
            #pragma unroll
            for(int i=0;i<4;i++)
                af[i] = *reinterpret_cast<const bf16x8*>(&zt[(i*16+mr)*ZP + k*32 + q*8]);
            #pragma unroll
            for(int i=0;i<4;i++)
                #pragma unroll
                for(int c=0;c<4;c++)
                    acc[i][c] = __builtin_amdgcn_mfma_f32_16x16x32_bf16(af[i], b0[c], acc[i][c], 0, 0, 0);
            if(k+1<NK){
                #pragma unroll
                for(int c=0;c<4;c++) b0[c]=b1[c];
            }
        }
    }

    if(!do_fc){
        // ---- epilogue: bias + relu + store + fused BN stats ----
        #pragma unroll
        for(int c=0;c<4;c++){
            int col = w*64 + c*16 + mr;
            float bv = b2f(bb[col]);
            float s = 0.f, s2 = 0.f;
            #pragma unroll
            for(int i=0;i<4;i++){
                int row = m0 + i*16 + q*4;
                #pragma unroll
                for(int r=0;r<4;r++){
                    float v = fmaxf(acc[i][c][r] + bv, 0.f);
                    u16 o = f2b(v);
                    C[(size_t)(row + r)*DIM + col] = o;
                    if(do_stats && (row + r) < NND){
                        float vr = b2f(o);
                        s += vr; s2 += vr*vr;
                    }
                }
            }
            if(do_stats){
                atomicAdd(&colS[col], s);
                atomicAdd(&colS2[col], s2);
            }
        }
        if(do_stats){
            __syncthreads();
            atomicAdd(&stats[tid], colS[tid]);
            atomicAdd(&stats[DIM+tid], colS2[tid]);
        }
    } else {
        // ---- layer-3 epilogue: h3 -> LDS, FC via MFMA, log-softmax, store out ----
        __syncthreads();
        #pragma unroll
        for(int c=0;c<4;c++){
            int col = w*64 + c*16 + mr;
            float bv = b2f(bb[col]);
            #pragma unroll
            for(int i=0;i<4;i++)
                #pragma unroll
                for(int r=0;r<4;r++)
                    zt[(i*16 + q*4 + r)*ZP + col] = f2b(fmaxf(acc[i][c][r] + bv, 0.f));
        }
        __syncthreads();
        f32x4 fa = (f32x4){0.f,0.f,0.f,0.f};
        #pragma unroll
        for(int k0=0; k0<DIM; k0+=32){
            bf16x8 za = *reinterpret_cast<const bf16x8*>(&zt[(w*16+mr)*ZP + k0 + q*8]);
            bf16x8 wb = *reinterpret_cast<const bf16x8*>(WfcT + (size_t)mr*DIM + k0 + q*8);
            fa = __builtin_amdgcn_mfma_f32_16x16x32_bf16(za, wb, fa, 0, 0, 0);
        }
        float bv = b2f(bfc[mr]);
        int f32o = mode[0];
        #pragma unroll
        for(int r=0;r<4;r++){
            float val = fa[r] + bv;
            float m = val;
            #pragma unroll
            for(int o=1;o<16;o<<=1) m = fmaxf(m, __shfl_xor(m, o));
            float ex = expf(val - m);
            float s = ex;
            #pragma unroll
            for(int o=1;o<16;o<<=1) s += __shfl_xor(s, o);
            float res = val - m - logf(s);
            int row = m0 + w*16 + q*4 + r;
            if(row < NND){
                if(f32o) ((float*)out)[(size_t)row*NC + mr] = res;
                else     ((u16*)out)[(size_t)row*NC + mr] = f2b(res);
            }
        }
    }
}

extern "C" void kernel_launch(void* const* d_in, const int* in_sizes, int n_in,
                              void* d_out, int out_size, void* d_ws, size_t ws_size,
                              hipStream_t stream){
    const void* x   = d_in[0];
    const int*  ei  = (const int*)d_in[1];
    const void* w1a = d_in[2];  const void* b1a = d_in[3];
    const void* w1b = d_in[4];  const void* b1b = d_in[5];
    const void* g1  = d_in[6];  const void* be1 = d_in[7];
    const void* w2a = d_in[8];  const void* b2a = d_in[9];
    const void* w2b = d_in[10]; const void* b2b = d_in[11];
    const void* g2  = d_in[12]; const void* be2 = d_in[13];
    const void* w3a = d_in[14]; const void* b3a = d_in[15];
    const void* w3b = d_in[16]; const void* b3b = d_in[17];
    const void* wfc = d_in[18]; const void* bfc = d_in[19];

    char* base = (char*)d_ws;
    size_t off = 0;
    auto alloc = [&](size_t bytes)->void*{
        void* p = base + off;
        off = (off + bytes + 255) & ~(size_t)255;
        return p;
    };
    u16*  P     = (u16*)alloc((size_t)MPAD*DIM*2);   // aliases Xc
    u16*  Q     = (u16*)alloc((size_t)MPAD*DIM*2);
    int*  ssrc  = (int*)alloc((size_t)NE*4);
    u32*  bArr  = (u32*)alloc((size_t)NBUCK*CAP*4);
    int*  gcur  = (int*)alloc((size_t)NBUCK*4);
    int*  rp    = (int*)alloc((size_t)(NND+1)*4);
    float* stats= (float*)alloc(4*DIM*4);            // statsA | statsB
    int*  mode  = (int*)alloc(16);
    u16* Wt1a = (u16*)alloc((size_t)F0*DIM*2);
    u16* Wt1b = (u16*)alloc((size_t)DIM*DIM*2);
    u16* Wt2a = (u16*)alloc((size_t)DIM*DIM*2);
    u16* Wt2b = (u16*)alloc((size_t)DIM*DIM*2);
    u16* Wt3a = (u16*)alloc((size_t)DIM*DIM*2);
    u16* Wt3b = (u16*)alloc((size_t)DIM*DIM*2);
    u16* Vc   = (u16*)alloc(11*256*2);
    u16* Wfc  = (u16*)alloc((size_t)DIM*NC*2);
    u16* Xc   = P;   // consumed by layer-1 agg before P is first written
    float* statsA = stats;
    float* statsB = stats + 2*DIM;

    probe_kernel<<<1, 256, 0, stream>>>((const u32*)x, ei, mode, gcur, stats);

    bucketA<<<(NE + EPB - 1)/EPB, 256, 0, stream>>>(ei, mode, bArr, gcur);
    bucketB<<<NBUCK, 256, 0, stream>>>(bArr, gcur, rp, ssrc);

    cvt_x<<<(NND*F0)/(256*8), 256, 0, stream>>>((const float*)x, Xc, mode);
    merged_cvt<<<128 + 5*256 + 16 + 11, 256, 0, stream>>>(
        w1a,w1b,w2a,w2b,w3a,w3b,wfc, b1a,b1b,g1,be1,b2a,b2b,g2,be2,b3a,b3b,bfc,
        Wt1a,Wt1b,Wt2a,Wt2b,Wt3a,Wt3b,Wfc,Vc, mode);

    int mgrid = MPAD/FBM;   // 1564

    // ---- layer 1 ----
    agg2<16><<<NND/4, 256, 0, stream>>>((const u16*)x, Xc, mode, rp, ssrc, Q,
                                        statsA, Vc, Vc, 0, NND);
    mlp_fused<F0><<<mgrid, 256, 0, stream>>>(Q, Wt1a, Vc+0*256, Wt1b, Vc+1*256, P,
                                             statsA, 1, 0, Wfc, Vc+10*256, d_out, mode);

    // ---- layer 2 (agg applies BN1 affine from statsA) ----
    agg2<32><<<NND/4, 256, 0, stream>>>(P, P, mode, rp, ssrc, Q,
                                        statsA, Vc+2*256, Vc+3*256, 1, NND);
    mlp_fused<DIM><<<mgrid, 256, 0, stream>>>(Q, Wt2a, Vc+4*256, Wt2b, Vc+5*256, P,
                                              statsB, 1, 0, Wfc, Vc+10*256, d_out, mode);

    // ---- layer 3 (agg applies BN2 affine from statsB; FC+lsm fused in epilogue) ----
    agg2<32><<<NND/4, 256, 0, stream>>>(P, P, mode, rp, ssrc, Q,
                                        statsB, Vc+6*256, Vc+7*256, 1, NND);
    mlp_fused<DIM><<<mgrid, 256, 0, stream>>>(Q, Wt3a, Vc+8*256, Wt3b, Vc+9*256, P,
                                              statsA, 0, 1, Wfc, Vc+10*256, d_out, mode);
}